// Round 19
// baseline (525.713 us; speedup 1.0000x reference)
//
#include <hip/hip_runtime.h>
#include <hip/hip_bf16.h>

// Problem constants
#define NB 64
#define NT 256
#define TC 16
#define NL 25
#define NWORDS 16384   // NB*NT
#define DWd 150        // word-LSTM input dim
#define WEd 100
#define WPB 5          // words per k_char block

__device__ __forceinline__ float sigf(float x){ return __fdividef(1.f, 1.f + __expf(-x)); }
__device__ __forceinline__ float tanhf_(float x){
    float ax = fabsf(x);
    float e = __expf(-2.f*ax);                 // e in (0,1], overflow-safe
    float r = (1.f - e) * __fdividef(1.f, 1.f + e);
    return copysignf(r, x);
}
__device__ __forceinline__ float RL(float v, int k){
    return __int_as_float(__builtin_amdgcn_readlane(__float_as_int(v), k));
}

// ---------------- Kernel 0: gxc precompute + meta zeroing (folded k_zero).
__global__ void k_gxc(const float* __restrict__ char_emb,
                      const float* __restrict__ cWih_f, const float* __restrict__ cb_f,
                      const float* __restrict__ cWih_b, const float* __restrict__ cb_b,
                      float* __restrict__ gxc, int* __restrict__ meta){
  int i = blockIdx.x*blockDim.x + threadIdx.x;
  if (blockIdx.x == 0 && threadIdx.x < 34) meta[threadIdx.x] = 0;
  if (i >= 128*2*100) return;
  int col = i % 100; int d = (i/100) & 1; int c = i/200;
  const float* Wih = d ? cWih_b : cWih_f;
  const float* bb  = d ? cb_b  : cb_f;
  float acc = bb[col];
  #pragma unroll
  for (int k=0;k<25;k++) acc += char_emb[c*25+k]*Wih[k*100+col];
  gxc[i] = acc;
}

// ---------------- Sort kernels: bucket words by char length (16 buckets).
__global__ __launch_bounds__(256) void k_hist(const int* __restrict__ char_lengths,
                                              int* __restrict__ hist){
  __shared__ int lh[16];
  int tid = threadIdx.x;
  if (tid < 16) lh[tid] = 0;
  __syncthreads();
  int w = blockIdx.x*256 + tid;
  atomicAdd(&lh[char_lengths[w]-1], 1);
  __syncthreads();
  if (tid < 16) atomicAdd(&hist[tid], lh[tid]);
}
__global__ void k_scan(const int* __restrict__ hist, int* __restrict__ cursor){
  if (threadIdx.x == 0){
    int acc = 0;
    for (int i=0;i<16;i++){ cursor[i] = acc; acc += hist[i]; }
  }
}
__global__ __launch_bounds__(256) void k_scatter(const int* __restrict__ char_lengths,
                                                 int* __restrict__ cursor,
                                                 int* __restrict__ widx){
  __shared__ int lh[16], lbase[16];
  int tid = threadIdx.x;
  if (tid < 16) lh[tid] = 0;
  __syncthreads();
  int w = blockIdx.x*256 + tid;
  int len = char_lengths[w]-1;
  int lrank = atomicAdd(&lh[len], 1);
  __syncthreads();
  if (tid < 16) lbase[tid] = atomicAdd(&cursor[tid], lh[tid]);
  __syncthreads();
  widx[lbase[len] + lrank] = w;
}

// ---------------- Kernel 1: char BiLSTM (R18 quad-gate, length-sorted).
__global__ __launch_bounds__(512) void k_char(const int* __restrict__ char_tensor,
   const int* __restrict__ char_lengths, const int* __restrict__ widx,
   const float* __restrict__ cWhh_f, const float* __restrict__ cWhh_b,
   const float* __restrict__ gxc, float* __restrict__ cf){
  __shared__ float h_lds[2][WPB][28];
  __shared__ int   chars[WPB][TC];
  __shared__ int   lens[WPB];
  __shared__ int   wids[WPB];
  int tid = threadIdx.x;
  int d  = blockIdx.x & 1;
  int wb = blockIdx.x >> 1;
  int w0 = wb*WPB;
  if (tid < WPB){
    int slot = w0 + tid; if (slot > NWORDS-1) slot = NWORDS-1;
    wids[tid] = widx[slot];
  }
  __syncthreads();
  if (tid < WPB*TC){
    int ww = wids[tid/TC];
    chars[tid/TC][tid%TC] = char_tensor[ww*TC + (tid%TC)];
  }
  if (tid < WPB) lens[tid] = char_lengths[wids[tid]];
  if (tid < 2*WPB*28){
    int p = tid/(WPB*28); int rr = tid - p*WPB*28;
    h_lds[p][rr/28][rr%28] = 0.f;
  }
  int wsub = tid/100;
  int r    = tid - wsub*100;   // 0..99
  int u    = r >> 2;           // unit 0..24
  int gid  = r & 3;            // gate: 0=i 1=f 2=g 3=o
  bool gate_thr = tid < WPB*100;
  int col = gid*25 + u;
  const float* Wh = d ? cWhh_b : cWhh_f;
  float wcol[25];
  if (gate_thr){
    #pragma unroll
    for (int k=0;k<25;k++) wcol[k] = Wh[k*100 + col];
  }
  float c_reg = 0.f, h_last = 0.f;
  __syncthreads();
  int lmax = lens[0];
  #pragma unroll
  for (int q=1;q<WPB;q++) lmax = max(lmax, lens[q]);
  int len = gate_thr ? lens[wsub] : 1;
  bool isg = (gid == 2);
  float gnext = 0.f;
  if (gate_thr){
    int ci = d ? (len-1) : 0;
    if (ci < 0 || ci >= TC) ci = 0;
    gnext = gxc[(size_t)(chars[wsub][ci]*2+d)*100 + col];
  }
  for (int t=0;t<lmax;t++){
    float gcur = gnext;
    if (gate_thr && t+1 < TC){
      int ci = d ? (len-2-t) : (t+1);
      if (ci < 0 || ci >= TC) ci = 0;
      gnext = gxc[(size_t)(chars[wsub][ci]*2+d)*100 + col];
    }
    float x = 0.f;
    if (gate_thr){
      float a0 = gcur, a1 = 0.f, a2 = 0.f, a3 = 0.f;
      const float4* h4 = (const float4*)h_lds[t&1][wsub];
      #pragma unroll
      for (int kq=0;kq<6;kq++){
        float4 hq = h4[kq];
        a0 += hq.x*wcol[4*kq];
        a1 += hq.y*wcol[4*kq+1];
        a2 += hq.z*wcol[4*kq+2];
        a3 += hq.w*wcol[4*kq+3];
      }
      a0 += h_lds[t&1][wsub][24]*wcol[24];
      float a = (a0+a1)+(a2+a3);
      x = isg ? tanhf_(a) : sigf(a);
    }
    float A = __shfl_xor(x, 1, 64);
    float B = __shfl_xor(x, 2, 64);
    float C = __shfl_xor(B, 1, 64);
    if (gate_thr && gid == 0){
      float hv;
      if (t < len){
        c_reg = A*c_reg + x*B;
        hv = C*tanhf_(c_reg);
        h_last = hv;
      } else hv = h_last;
      h_lds[(t+1)&1][wsub][u] = hv;
    }
    __syncthreads();
  }
  if (gate_thr && gid == 0){
    int w = wids[wsub];
    cf[(size_t)w*56 + d*28 + u] = h_last;
  }
}

// ---------------- Kernel 3: gx[d][p][400] = wb_d + [word_emb[tok[p]] ++ cf[recover[p]]] @ wWih_d
__global__ __launch_bounds__(256) void k_wih(const int* __restrict__ tok,
    const int* __restrict__ recover,
    const float* __restrict__ word_emb, const float* __restrict__ cf,
    const float* __restrict__ Wf, const float* __restrict__ bf,
    const float* __restrict__ Wb, const float* __restrict__ bbias,
    float* __restrict__ gx){
  __shared__ float As[150][72];
  __shared__ int toks[64], recs[64];
  int tid = threadIdx.x;
  int m0 = (blockIdx.x>>2)*64;
  int nt = blockIdx.x & 3;
  int n0 = nt*256;
  if (tid < 64) toks[tid] = tok[m0 + tid];
  else if (tid < 128) recs[tid-64] = recover[m0 + tid - 64];
  __syncthreads();
  for (int i=tid; i<64*150; i+=256){
    int r = i/150; int k = i - r*150;
    float v;
    if (k < WEd) v = word_emb[(long)toks[r]*WEd + k];
    else {
      int ci = k - WEd;
      int dd = ci/25; int uu = ci - dd*25;
      v = cf[(size_t)recs[r]*56 + dd*28 + uu];
    }
    As[k][r] = v;
  }
  __syncthreads();
  int tn = tid & 31; int tm = tid >> 5;
  int j0 = n0 + tn*8;
  bool colok = j0 < 800;
  int d = (j0 >= 400) ? 1 : 0;
  const float* W = d ? Wb : Wf;
  int jc = j0 - d*400;
  float acc[8][8];
  #pragma unroll
  for (int mi=0;mi<8;mi++)
    #pragma unroll
    for (int ni=0;ni<8;ni++) acc[mi][ni]=0.f;
  if (colok){
    for (int k=0;k<150;k++){
      float4 b0 = *(const float4*)&W[k*400 + jc];
      float4 b1 = *(const float4*)&W[k*400 + jc + 4];
      float4 a0 = *(const float4*)&As[k][tm*8];
      float4 a1 = *(const float4*)&As[k][tm*8+4];
      float av[8] = {a0.x,a0.y,a0.z,a0.w,a1.x,a1.y,a1.z,a1.w};
      float bv[8] = {b0.x,b0.y,b0.z,b0.w,b1.x,b1.y,b1.z,b1.w};
      #pragma unroll
      for (int mi=0;mi<8;mi++)
        #pragma unroll
        for (int ni=0;ni<8;ni++) acc[mi][ni] += av[mi]*bv[ni];
    }
    const float* bptr = d ? bbias : bf;
    float bias[8];
    #pragma unroll
    for (int ni=0;ni<8;ni++) bias[ni] = bptr[jc+ni];
    #pragma unroll
    for (int mi=0;mi<8;mi++){
      int p = m0 + tm*8 + mi;
      float* orow = gx + ((long)d*NWORDS + p)*400 + jc;
      #pragma unroll
      for (int ni=0;ni<8;ni++) orow[ni] = acc[mi][ni] + bias[ni];
    }
  }
}

// ---------------- Kernel 4: word LSTM recurrence v5 — quad-gate lanes, ONE barrier/step.
// thread = (unit u=tid>>2, gate g=tid&3): unit's 4 gate cols in adjacent lanes.
// Gate exchange via 3 shfl_xor (no act LDS); c in gid0 lane's register; h
// parity-buffered in LDS -> single barrier per step.
__global__ __launch_bounds__(448, 2) void k_wlstm(const float* __restrict__ gx,
     const float* __restrict__ Whf, const float* __restrict__ Whb,
     float* __restrict__ hseq){
  __shared__ float wstage[10000];   // 25 rows x 400 cols, 40KB chunk
  __shared__ float h_lds[2][100];
  int tid = threadIdx.x;
  int s = blockIdx.x & 63; int d = blockIdx.x >> 6;
  const float* Wh = d ? Whb : Whf;
  int u   = tid >> 2;
  int gid = tid & 3;
  bool colthr = tid < 400;
  int col = gid*100 + u;
  float wreg[100];
  #pragma unroll
  for (int ch=0; ch<4; ch++){
    for (int i=tid; i<2500; i+=448)
      ((float4*)wstage)[i] = ((const float4*)(Wh + ch*10000))[i];
    __syncthreads();
    if (colthr){
      #pragma unroll
      for (int kk=0;kk<25;kk++) wreg[ch*25+kk] = wstage[kk*400 + col];
    }
    __syncthreads();
  }
  if (tid < 200) h_lds[tid/100][tid%100] = 0.f;
  float c_reg = 0.f;
  const float* gxd = gx + ((long)d*NWORDS + (long)s*256)*400;
  bool isg = (gid == 2);
  __syncthreads();
  float gnext = 0.f;
  if (colthr) gnext = gxd[(d?255:0)*400 + col];
  for (int t=0;t<256;t++){
    float gcur = gnext;
    if (colthr && t+1 < 256){
      int tn = d ? (255-(t+1)) : (t+1);
      gnext = gxd[tn*400 + col];
    }
    float x = 0.f;
    if (colthr){
      float a0 = gcur, a1 = 0.f, a2 = 0.f, a3 = 0.f;
      const float4* h4 = (const float4*)h_lds[t&1];
      #pragma unroll
      for (int kq=0;kq<25;kq++){
        float4 hq = h4[kq];
        a0 += hq.x*wreg[4*kq];
        a1 += hq.y*wreg[4*kq+1];
        a2 += hq.z*wreg[4*kq+2];
        a3 += hq.w*wreg[4*kq+3];
      }
      float a = (a0+a1)+(a2+a3);
      x = isg ? tanhf_(a) : sigf(a);
    }
    float A = __shfl_xor(x, 1, 64);   // gid^1
    float B = __shfl_xor(x, 2, 64);   // gid^2
    float C = __shfl_xor(B, 1, 64);   // gid^3
    if (colthr && gid == 0){
      // x=i, A=f, B=g, C=o (activated)
      c_reg = A*c_reg + x*B;
      float hv = C*tanhf_(c_reg);
      h_lds[(t+1)&1][u] = hv;
      int ttc = d ? (255-t) : t;
      hseq[((long)d*NWORDS + s*256 + ttc)*100 + u] = hv;
    }
    __syncthreads();   // new h visible (parity buffer: no read/write race)
  }
}

// ---------------- Kernel 5: emissions em[p][25] = b_tag + concat(h_f,h_b)[p] @ W_tag
__global__ __launch_bounds__(256) void k_em(const float* __restrict__ hseq,
    const float* __restrict__ Wtag, const float* __restrict__ btag,
    float* __restrict__ em){
  __shared__ float hrow[8][200];
  __shared__ float WsT[25][204];
  int tid = threadIdx.x;
  for (int i=tid;i<5000;i+=256){
    int c = i/200; int k = i - c*200;
    WsT[c][k] = Wtag[k*25 + c];
  }
  int p0 = blockIdx.x*8;
  for (int i=tid;i<8*200;i+=256){
    int r = i/200; int k = i - r*200;
    int p = p0+r;
    hrow[r][k] = (k<100) ? hseq[(long)p*100+k] : hseq[((long)NWORDS + p)*100 + (k-100)];
  }
  __syncthreads();
  int r = tid>>5; int c = tid&31;
  if (c<25){
    float a0=0.f,a1=0.f,a2=0.f,a3=0.f;
    #pragma unroll 10
    for (int k=0;k<200;k+=4){
      float4 h4 = *(const float4*)&hrow[r][k];
      float4 w4 = *(const float4*)&WsT[c][k];
      a0 += h4.x*w4.x; a1 += h4.y*w4.y;
      a2 += h4.z*w4.z; a3 += h4.w*w4.w;
    }
    em[(long)(p0+r)*25 + c] = btag[c] + (a0+a1)+(a2+a3);
  }
}

// ---------------- Kernel 6: CRF per sequence (1 exp/step via etr precompute).
__global__ __launch_bounds__(64) void k_crf(const float* __restrict__ em,
    const int* __restrict__ tag, const float* __restrict__ trans,
    const float* __restrict__ start, const float* __restrict__ endv,
    float* __restrict__ part){
  int s = blockIdx.x;
  int lane = threadIdx.x;
  const float* emb = em + (long)s*256*25;
  float etr[25];
  #pragma unroll
  for (int k=0;k<25;k++) etr[k] = (lane<25) ? __expf(trans[k*25+lane]) : 0.f;
  float alpha = (lane<25) ? (start[lane] + emb[lane]) : 0.f;
  float enext = (lane<25) ? emb[25+lane] : 0.f;
  for (int t=1;t<256;t++){
    float ecur = enext;
    if (t<255 && lane<25) enext = emb[(t+1)*25 + lane];
    float base = RL(alpha, 0);
    float e = __expf(alpha - base);
    float s0=0.f,s1=0.f,s2=0.f,s3=0.f,s4=0.f;
    #pragma unroll
    for (int k=0;k<5;k++) s0 += RL(e,k)    * etr[k];
    #pragma unroll
    for (int k=0;k<5;k++) s1 += RL(e,5+k)  * etr[5+k];
    #pragma unroll
    for (int k=0;k<5;k++) s2 += RL(e,10+k) * etr[10+k];
    #pragma unroll
    for (int k=0;k<5;k++) s3 += RL(e,15+k) * etr[15+k];
    #pragma unroll
    for (int k=0;k<5;k++) s4 += RL(e,20+k) * etr[20+k];
    float ssum = ((s0+s1)+(s2+s3))+s4;
    alpha = __logf(ssum) + base + ecur;
  }
  float val = (lane<25) ? (alpha + endv[lane]) : -1e30f;
  float m2 = -1e30f;
  #pragma unroll
  for (int k=0;k<25;k++) m2 = fmaxf(m2, RL(val,k));
  float s2s = 0.f;
  #pragma unroll
  for (int k=0;k<25;k++) s2s += __expf(RL(val,k) - m2);
  float logZ = __logf(s2s) + m2;
  const int* tg = tag + s*256;
  float gp = 0.f;
  for (int t=lane; t<256; t+=64){
    int a = tg[t];
    gp += emb[t*25 + a];
    if (t<255) gp += trans[a*25 + tg[t+1]];
  }
  #pragma unroll
  for (int off=32; off; off>>=1) gp += __shfl_xor(gp, off, 64);
  if (lane==0){
    float gold = gp + start[tg[0]] + endv[tg[255]];
    part[s] = logZ - gold;
  }
}

// ---------------- Kernel 7: final reduce
__global__ __launch_bounds__(64) void k_red(const float* __restrict__ part, float* __restrict__ out){
  float v = part[threadIdx.x];
  #pragma unroll
  for (int off=32; off; off>>=1) v += __shfl_xor(v, off, 64);
  if (threadIdx.x==0) out[0] = v;
}

extern "C" void kernel_launch(void* const* d_in, const int* in_sizes, int n_in,
                              void* d_out, int out_size, void* d_ws, size_t ws_size,
                              hipStream_t stream){
  const int* tok          = (const int*)d_in[0];
  const int* tagp         = (const int*)d_in[1];
  const int* char_tensor  = (const int*)d_in[3];
  const int* char_lengths = (const int*)d_in[4];
  const int* recover      = (const int*)d_in[5];
  const float* word_emb = (const float*)d_in[6];
  const float* char_emb = (const float*)d_in[7];
  const float* cWih_f=(const float*)d_in[8];  const float* cWhh_f=(const float*)d_in[9];  const float* cb_f=(const float*)d_in[10];
  const float* cWih_b=(const float*)d_in[11]; const float* cWhh_b=(const float*)d_in[12]; const float* cb_b=(const float*)d_in[13];
  const float* wWih_f=(const float*)d_in[14]; const float* wWhh_f=(const float*)d_in[15]; const float* wb_f=(const float*)d_in[16];
  const float* wWih_b=(const float*)d_in[17]; const float* wWhh_b=(const float*)d_in[18]; const float* wb_b=(const float*)d_in[19];
  const float* W_tag=(const float*)d_in[20];  const float* b_tag=(const float*)d_in[21];
  const float* trans=(const float*)d_in[22];  const float* startv=(const float*)d_in[23]; const float* endv=(const float*)d_in[24];

  float* ws  = (float*)d_ws;
  float* gxc = ws;                 // [0, 25600)
  float* cf  = ws + 25600;         // [25600, 943104)
  float* gx  = ws + 943104;        // [943104, 14050304)
  float* hseq= ws + 14050304;      // [14050304, 17327104)
  float* em  = ws;                 // overlays gxc+cf (dead after k_wih), 409600
  float* part= ws + 17327104;      // 64
  int*   meta= (int*)(ws + 17327168);  // hist[16]+cursor[16]+pad
  int*   widx= meta + 64;              // 16384 ints (high water ~69.4 MB)
  float* out = (float*)d_out;

  k_gxc    <<<100, 256, 0, stream>>>(char_emb, cWih_f, cb_f, cWih_b, cb_b, gxc, meta);
  k_hist   <<<64,  256, 0, stream>>>(char_lengths, meta);
  k_scan   <<<1,   64,  0, stream>>>(meta, meta+16);
  k_scatter<<<64,  256, 0, stream>>>(char_lengths, meta+16, widx);
  k_char   <<<6554,512, 0, stream>>>(char_tensor, char_lengths, widx, cWhh_f, cWhh_b, gxc, cf);
  k_wih    <<<1024,256, 0, stream>>>(tok, recover, word_emb, cf, wWih_f, wb_f, wWih_b, wb_b, gx);
  k_wlstm  <<<128, 448, 0, stream>>>(gx, wWhh_f, wWhh_b, hseq);
  k_em     <<<2048,256, 0, stream>>>(hseq, W_tag, b_tag, em);
  k_crf    <<<64,  64,  0, stream>>>(em, tagp, trans, startv, endv, part);
  k_red    <<<1,   64,  0, stream>>>(part, out);
}

// Round 20
// 507.272 us; speedup vs baseline: 1.0364x; 1.0364x over previous
//
#include <hip/hip_runtime.h>
#include <hip/hip_bf16.h>

// Problem constants
#define NB 64
#define NT 256
#define TC 16
#define NL 25
#define NWORDS 16384   // NB*NT
#define DWd 150        // word-LSTM input dim
#define WEd 100
#define WPB 5          // words per k_char block

__device__ __forceinline__ float sigf(float x){ return __fdividef(1.f, 1.f + __expf(-x)); }
__device__ __forceinline__ float tanhf_(float x){
    float ax = fabsf(x);
    float e = __expf(-2.f*ax);                 // e in (0,1], overflow-safe
    float r = (1.f - e) * __fdividef(1.f, 1.f + e);
    return copysignf(r, x);
}
__device__ __forceinline__ float RL(float v, int k){
    return __int_as_float(__builtin_amdgcn_readlane(__float_as_int(v), k));
}

// ---------------- Kernel 0: gxc precompute + meta zeroing (folded).
__global__ void k_gxc(const float* __restrict__ char_emb,
                      const float* __restrict__ cWih_f, const float* __restrict__ cb_f,
                      const float* __restrict__ cWih_b, const float* __restrict__ cb_b,
                      float* __restrict__ gxc, int* __restrict__ meta){
  int i = blockIdx.x*blockDim.x + threadIdx.x;
  if (blockIdx.x == 0 && threadIdx.x < 34) meta[threadIdx.x] = 0;
  if (i >= 128*2*100) return;
  int col = i % 100; int d = (i/100) & 1; int c = i/200;
  const float* Wih = d ? cWih_b : cWih_f;
  const float* bb  = d ? cb_b  : cb_f;
  float acc = bb[col];
  #pragma unroll
  for (int k=0;k<25;k++) acc += char_emb[c*25+k]*Wih[k*100+col];
  gxc[i] = acc;
}

// ---------------- Sort kernels: bucket words by char length (16 buckets).
__global__ __launch_bounds__(256) void k_hist(const int* __restrict__ char_lengths,
                                              int* __restrict__ hist){
  __shared__ int lh[16];
  int tid = threadIdx.x;
  if (tid < 16) lh[tid] = 0;
  __syncthreads();
  int w = blockIdx.x*256 + tid;
  atomicAdd(&lh[char_lengths[w]-1], 1);
  __syncthreads();
  if (tid < 16) atomicAdd(&hist[tid], lh[tid]);
}
__global__ void k_scan(const int* __restrict__ hist, int* __restrict__ cursor){
  if (threadIdx.x == 0){
    int acc = 0;
    for (int i=0;i<16;i++){ cursor[i] = acc; acc += hist[i]; }
  }
}
__global__ __launch_bounds__(256) void k_scatter(const int* __restrict__ char_lengths,
                                                 int* __restrict__ cursor,
                                                 int* __restrict__ widx){
  __shared__ int lh[16], lbase[16];
  int tid = threadIdx.x;
  if (tid < 16) lh[tid] = 0;
  __syncthreads();
  int w = blockIdx.x*256 + tid;
  int len = char_lengths[w]-1;
  int lrank = atomicAdd(&lh[len], 1);
  __syncthreads();
  if (tid < 16) lbase[tid] = atomicAdd(&cursor[tid], lh[tid]);
  __syncthreads();
  widx[lbase[len] + lrank] = w;
}

// ---------------- Kernel 1: char BiLSTM over length-sorted words (R16 version:
// act LDS exchange, 4-partial-sum chains, gcur/gnext named-register prefetch).
__global__ __launch_bounds__(512) void k_char(const int* __restrict__ char_tensor,
   const int* __restrict__ char_lengths, const int* __restrict__ widx,
   const float* __restrict__ cWhh_f, const float* __restrict__ cWhh_b,
   const float* __restrict__ gxc, float* __restrict__ cf){
  __shared__ float h_lds[WPB][28];
  __shared__ float act[WPB][100];
  __shared__ int   chars[WPB][TC];
  __shared__ int   lens[WPB];
  __shared__ int   wids[WPB];
  int tid = threadIdx.x;
  int d  = blockIdx.x & 1;
  int wb = blockIdx.x >> 1;
  int w0 = wb*WPB;
  if (tid < WPB){
    int slot = w0 + tid; if (slot > NWORDS-1) slot = NWORDS-1;
    wids[tid] = widx[slot];
  }
  __syncthreads();
  if (tid < WPB*TC){
    int ww = wids[tid/TC];
    chars[tid/TC][tid%TC] = char_tensor[ww*TC + (tid%TC)];
  }
  if (tid < WPB) lens[tid] = char_lengths[wids[tid]];
  int wsub = tid/100;
  int j    = tid - wsub*100;
  bool gate_thr = tid < WPB*100;
  const float* Wh = d ? cWhh_b : cWhh_f;
  float wcol[25];
  if (gate_thr){
    #pragma unroll
    for (int k=0;k<25;k++) wcol[k] = Wh[k*100 + j];
  }
  if (gate_thr && j < 28) h_lds[wsub][j] = 0.f;
  float c_reg = 0.f, h_last = 0.f;
  __syncthreads();
  int lmax = lens[0];
  #pragma unroll
  for (int q=1;q<WPB;q++) lmax = max(lmax, lens[q]);
  int len = gate_thr ? lens[wsub] : 1;
  bool isg = (j >= 50) && (j < 75);
  float gnext = 0.f;
  if (gate_thr){
    int ci = d ? (len-1) : 0;
    if (ci < 0 || ci >= TC) ci = 0;
    gnext = gxc[(size_t)(chars[wsub][ci]*2+d)*100 + j];
  }
  for (int t=0;t<lmax;t++){
    float gcur = gnext;
    if (gate_thr && t+1 < TC){
      int ci = d ? (len-2-t) : (t+1);
      if (ci < 0 || ci >= TC) ci = 0;
      gnext = gxc[(size_t)(chars[wsub][ci]*2+d)*100 + j];
    }
    if (gate_thr){
      float a0 = gcur, a1 = 0.f, a2 = 0.f, a3 = 0.f;
      const float4* h4 = (const float4*)h_lds[wsub];
      #pragma unroll
      for (int kq=0;kq<6;kq++){
        float4 hq = h4[kq];
        a0 += hq.x*wcol[4*kq];
        a1 += hq.y*wcol[4*kq+1];
        a2 += hq.z*wcol[4*kq+2];
        a3 += hq.w*wcol[4*kq+3];
      }
      a0 += h_lds[wsub][24]*wcol[24];
      float a = (a0+a1)+(a2+a3);
      act[wsub][j] = isg ? tanhf_(a) : sigf(a);
    }
    __syncthreads();
    if (gate_thr && j < 25 && t < len){
      float si = act[wsub][j], sf = act[wsub][25+j], sg = act[wsub][50+j], so = act[wsub][75+j];
      c_reg = sf*c_reg + si*sg;
      float hv = so*tanhf_(c_reg);
      h_lds[wsub][j] = hv;
      h_last = hv;
    }
    __syncthreads();
  }
  if (gate_thr && j < 25){
    int w = wids[wsub];
    cf[(size_t)w*56 + d*28 + j] = h_last;
  }
}

// ---------------- Kernel 3: gx[d][p][400] = wb_d + [word_emb[tok[p]] ++ cf[recover[p]]] @ wWih_d
__global__ __launch_bounds__(256) void k_wih(const int* __restrict__ tok,
    const int* __restrict__ recover,
    const float* __restrict__ word_emb, const float* __restrict__ cf,
    const float* __restrict__ Wf, const float* __restrict__ bf,
    const float* __restrict__ Wb, const float* __restrict__ bbias,
    float* __restrict__ gx){
  __shared__ float As[150][72];
  __shared__ int toks[64], recs[64];
  int tid = threadIdx.x;
  int m0 = (blockIdx.x>>2)*64;
  int nt = blockIdx.x & 3;
  int n0 = nt*256;
  if (tid < 64) toks[tid] = tok[m0 + tid];
  else if (tid < 128) recs[tid-64] = recover[m0 + tid - 64];
  __syncthreads();
  for (int i=tid; i<64*150; i+=256){
    int r = i/150; int k = i - r*150;
    float v;
    if (k < WEd) v = word_emb[(long)toks[r]*WEd + k];
    else {
      int ci = k - WEd;
      int dd = ci/25; int uu = ci - dd*25;
      v = cf[(size_t)recs[r]*56 + dd*28 + uu];
    }
    As[k][r] = v;
  }
  __syncthreads();
  int tn = tid & 31; int tm = tid >> 5;
  int j0 = n0 + tn*8;
  bool colok = j0 < 800;
  int d = (j0 >= 400) ? 1 : 0;
  const float* W = d ? Wb : Wf;
  int jc = j0 - d*400;
  float acc[8][8];
  #pragma unroll
  for (int mi=0;mi<8;mi++)
    #pragma unroll
    for (int ni=0;ni<8;ni++) acc[mi][ni]=0.f;
  if (colok){
    for (int k=0;k<150;k++){
      float4 b0 = *(const float4*)&W[k*400 + jc];
      float4 b1 = *(const float4*)&W[k*400 + jc + 4];
      float4 a0 = *(const float4*)&As[k][tm*8];
      float4 a1 = *(const float4*)&As[k][tm*8+4];
      float av[8] = {a0.x,a0.y,a0.z,a0.w,a1.x,a1.y,a1.z,a1.w};
      float bv[8] = {b0.x,b0.y,b0.z,b0.w,b1.x,b1.y,b1.z,b1.w};
      #pragma unroll
      for (int mi=0;mi<8;mi++)
        #pragma unroll
        for (int ni=0;ni<8;ni++) acc[mi][ni] += av[mi]*bv[ni];
    }
    const float* bptr = d ? bbias : bf;
    float bias[8];
    #pragma unroll
    for (int ni=0;ni<8;ni++) bias[ni] = bptr[jc+ni];
    #pragma unroll
    for (int mi=0;mi<8;mi++){
      int p = m0 + tm*8 + mi;
      float* orow = gx + ((long)d*NWORDS + p)*400 + jc;
      #pragma unroll
      for (int ni=0;ni<8;ni++) orow[ni] = acc[mi][ni] + bias[ni];
    }
  }
}

// ---------------- Kernel 4: word LSTM recurrence (R16 exact: v4 + 4-partial-sum chains,
// plain __syncthreads, 1-deep gx prefetch — best measured 226us, absmax 0).
__global__ __launch_bounds__(448, 2) void k_wlstm(const float* __restrict__ gx,
     const float* __restrict__ Whf, const float* __restrict__ Whb,
     float* __restrict__ hseq){
  __shared__ float wstage[10000];   // 25 rows x 400 cols, 40KB chunk
  __shared__ float h_lds[100];
  __shared__ float act[400];
  int tid = threadIdx.x;
  int s = blockIdx.x & 63; int d = blockIdx.x >> 6;
  const float* Wh = d ? Whb : Whf;
  int j = tid;
  bool colthr = j < 400;
  float wreg[100];
  #pragma unroll
  for (int ch=0; ch<4; ch++){
    for (int i=tid; i<2500; i+=448)
      ((float4*)wstage)[i] = ((const float4*)(Wh + ch*10000))[i];
    __syncthreads();
    if (colthr){
      #pragma unroll
      for (int kk=0;kk<25;kk++) wreg[ch*25+kk] = wstage[kk*400 + j];
    }
    __syncthreads();
  }
  if (tid < 100) h_lds[tid] = 0.f;
  float c_reg = 0.f;
  const float* gxd = gx + ((long)d*NWORDS + (long)s*256)*400;
  bool isg = (j >= 200) && (j < 300);
  __syncthreads();
  float gnext = 0.f;
  if (colthr) gnext = gxd[(d?255:0)*400 + j];
  for (int t=0;t<256;t++){
    float gcur = gnext;
    if (colthr && t+1 < 256){
      int tn = d ? (255-(t+1)) : (t+1);
      gnext = gxd[tn*400 + j];
    }
    if (colthr){
      float a0 = gcur, a1 = 0.f, a2 = 0.f, a3 = 0.f;
      const float4* h4 = (const float4*)h_lds;
      #pragma unroll
      for (int kq=0;kq<25;kq++){
        float4 hq = h4[kq];
        a0 += hq.x*wreg[4*kq];
        a1 += hq.y*wreg[4*kq+1];
        a2 += hq.z*wreg[4*kq+2];
        a3 += hq.w*wreg[4*kq+3];
      }
      float a = (a0+a1)+(a2+a3);
      act[j] = isg ? tanhf_(a) : sigf(a);
    }
    __syncthreads();   // act visible; all h_lds reads of this step done
    if (tid < 100){
      float si = act[tid], sf = act[100+tid], sg = act[200+tid], so = act[300+tid];
      c_reg = sf*c_reg + si*sg;
      float hv = so*tanhf_(c_reg);
      h_lds[tid] = hv;
      int ttc = d ? (255-t) : t;
      hseq[((long)d*NWORDS + s*256 + ttc)*100 + tid] = hv;
    }
    __syncthreads();   // new h visible
  }
}

// ---------------- Kernel 5: emissions em[p][25] = b_tag + concat(h_f,h_b)[p] @ W_tag (R16 version)
__global__ __launch_bounds__(256) void k_em(const float* __restrict__ hseq,
    const float* __restrict__ Wtag, const float* __restrict__ btag,
    float* __restrict__ em){
  __shared__ float hrow[8][200];
  __shared__ float Ws[5000];
  int tid = threadIdx.x;
  for (int i=tid;i<5000;i+=256) Ws[i] = Wtag[i];
  int p0 = blockIdx.x*8;
  for (int i=tid;i<8*200;i+=256){
    int r = i/200; int k = i - r*200;
    int p = p0+r;
    hrow[r][k] = (k<100) ? hseq[(long)p*100+k] : hseq[((long)NWORDS + p)*100 + (k-100)];
  }
  __syncthreads();
  int r = tid>>5; int c = tid&31;
  if (c<25){
    float acc = btag[c];
    for (int k=0;k<200;k++) acc += hrow[r][k]*Ws[k*25+c];
    em[(long)(p0+r)*25 + c] = acc;
  }
}

// ---------------- Kernel 6: CRF per sequence (R17: 1 exp/step via etr precompute).
__global__ __launch_bounds__(64) void k_crf(const float* __restrict__ em,
    const int* __restrict__ tag, const float* __restrict__ trans,
    const float* __restrict__ start, const float* __restrict__ endv,
    float* __restrict__ part){
  int s = blockIdx.x;
  int lane = threadIdx.x;
  const float* emb = em + (long)s*256*25;
  float etr[25];
  #pragma unroll
  for (int k=0;k<25;k++) etr[k] = (lane<25) ? __expf(trans[k*25+lane]) : 0.f;
  float alpha = (lane<25) ? (start[lane] + emb[lane]) : 0.f;
  float enext = (lane<25) ? emb[25+lane] : 0.f;
  for (int t=1;t<256;t++){
    float ecur = enext;
    if (t<255 && lane<25) enext = emb[(t+1)*25 + lane];
    float base = RL(alpha, 0);
    float e = __expf(alpha - base);
    float s0=0.f,s1=0.f,s2=0.f,s3=0.f,s4=0.f;
    #pragma unroll
    for (int k=0;k<5;k++) s0 += RL(e,k)    * etr[k];
    #pragma unroll
    for (int k=0;k<5;k++) s1 += RL(e,5+k)  * etr[5+k];
    #pragma unroll
    for (int k=0;k<5;k++) s2 += RL(e,10+k) * etr[10+k];
    #pragma unroll
    for (int k=0;k<5;k++) s3 += RL(e,15+k) * etr[15+k];
    #pragma unroll
    for (int k=0;k<5;k++) s4 += RL(e,20+k) * etr[20+k];
    float ssum = ((s0+s1)+(s2+s3))+s4;
    alpha = __logf(ssum) + base + ecur;
  }
  float val = (lane<25) ? (alpha + endv[lane]) : -1e30f;
  float m2 = -1e30f;
  #pragma unroll
  for (int k=0;k<25;k++) m2 = fmaxf(m2, RL(val,k));
  float s2s = 0.f;
  #pragma unroll
  for (int k=0;k<25;k++) s2s += __expf(RL(val,k) - m2);
  float logZ = __logf(s2s) + m2;
  const int* tg = tag + s*256;
  float gp = 0.f;
  for (int t=lane; t<256; t+=64){
    int a = tg[t];
    gp += emb[t*25 + a];
    if (t<255) gp += trans[a*25 + tg[t+1]];
  }
  #pragma unroll
  for (int off=32; off; off>>=1) gp += __shfl_xor(gp, off, 64);
  if (lane==0){
    float gold = gp + start[tg[0]] + endv[tg[255]];
    part[s] = logZ - gold;
  }
}

// ---------------- Kernel 7: final reduce
__global__ __launch_bounds__(64) void k_red(const float* __restrict__ part, float* __restrict__ out){
  float v = part[threadIdx.x];
  #pragma unroll
  for (int off=32; off; off>>=1) v += __shfl_xor(v, off, 64);
  if (threadIdx.x==0) out[0] = v;
}

extern "C" void kernel_launch(void* const* d_in, const int* in_sizes, int n_in,
                              void* d_out, int out_size, void* d_ws, size_t ws_size,
                              hipStream_t stream){
  const int* tok          = (const int*)d_in[0];
  const int* tagp         = (const int*)d_in[1];
  const int* char_tensor  = (const int*)d_in[3];
  const int* char_lengths = (const int*)d_in[4];
  const int* recover      = (const int*)d_in[5];
  const float* word_emb = (const float*)d_in[6];
  const float* char_emb = (const float*)d_in[7];
  const float* cWih_f=(const float*)d_in[8];  const float* cWhh_f=(const float*)d_in[9];  const float* cb_f=(const float*)d_in[10];
  const float* cWih_b=(const float*)d_in[11]; const float* cWhh_b=(const float*)d_in[12]; const float* cb_b=(const float*)d_in[13];
  const float* wWih_f=(const float*)d_in[14]; const float* wWhh_f=(const float*)d_in[15]; const float* wb_f=(const float*)d_in[16];
  const float* wWih_b=(const float*)d_in[17]; const float* wWhh_b=(const float*)d_in[18]; const float* wb_b=(const float*)d_in[19];
  const float* W_tag=(const float*)d_in[20];  const float* b_tag=(const float*)d_in[21];
  const float* trans=(const float*)d_in[22];  const float* startv=(const float*)d_in[23]; const float* endv=(const float*)d_in[24];

  float* ws  = (float*)d_ws;
  float* gxc = ws;                 // [0, 25600)
  float* cf  = ws + 25600;         // [25600, 943104)
  float* gx  = ws + 943104;        // [943104, 14050304)
  float* hseq= ws + 14050304;      // [14050304, 17327104)
  float* em  = ws;                 // overlays gxc+cf (dead after k_wih), 409600
  float* part= ws + 17327104;      // 64
  int*   meta= (int*)(ws + 17327168);  // hist[16]+cursor[16]+pad
  int*   widx= meta + 64;              // 16384 ints (high water ~69.4 MB)
  float* out = (float*)d_out;

  k_gxc    <<<100, 256, 0, stream>>>(char_emb, cWih_f, cb_f, cWih_b, cb_b, gxc, meta);
  k_hist   <<<64,  256, 0, stream>>>(char_lengths, meta);
  k_scan   <<<1,   64,  0, stream>>>(meta, meta+16);
  k_scatter<<<64,  256, 0, stream>>>(char_lengths, meta+16, widx);
  k_char   <<<6554,512, 0, stream>>>(char_tensor, char_lengths, widx, cWhh_f, cWhh_b, gxc, cf);
  k_wih    <<<1024,256, 0, stream>>>(tok, recover, word_emb, cf, wWih_f, wb_f, wWih_b, wb_b, gx);
  k_wlstm  <<<128, 448, 0, stream>>>(gx, wWhh_f, wWhh_b, hseq);
  k_em     <<<2048,256, 0, stream>>>(hseq, W_tag, b_tag, em);
  k_crf    <<<64,  64,  0, stream>>>(em, tagp, trans, startv, endv, part);
  k_red    <<<1,   64,  0, stream>>>(part, out);
}

// Round 21
// 506.021 us; speedup vs baseline: 1.0389x; 1.0025x over previous
//
#include <hip/hip_runtime.h>
#include <hip/hip_bf16.h>

// Problem constants
#define NB 64
#define NT 256
#define TC 16
#define NL 25
#define NWORDS 16384   // NB*NT
#define DWd 150        // word-LSTM input dim
#define WEd 100
#define WPB 5          // words per k_char block

__device__ __forceinline__ float sigf(float x){ return __fdividef(1.f, 1.f + __expf(-x)); }
__device__ __forceinline__ float tanhf_(float x){
    float ax = fabsf(x);
    float e = __expf(-2.f*ax);                 // e in (0,1], overflow-safe
    float r = (1.f - e) * __fdividef(1.f, 1.f + e);
    return copysignf(r, x);
}
__device__ __forceinline__ float RL(float v, int k){
    return __int_as_float(__builtin_amdgcn_readlane(__float_as_int(v), k));
}

// ---------------- Kernel 0: gxc precompute + per-block length histograms.
// Blocks 0..63 each write an EXCLUSIVE partial histogram hist64[b][16]
// (LDS-accumulated, full overwrite -> no global atomics, no pre-zeroing).
__global__ void k_gxc(const float* __restrict__ char_emb,
                      const float* __restrict__ cWih_f, const float* __restrict__ cb_f,
                      const float* __restrict__ cWih_b, const float* __restrict__ cb_b,
                      const int* __restrict__ char_lengths,
                      float* __restrict__ gxc, int* __restrict__ hist64){
  __shared__ int lh[16];
  int tid = threadIdx.x;
  bool histblk = blockIdx.x < 64;
  if (histblk){
    if (tid < 16) lh[tid] = 0;
    __syncthreads();
    int w = blockIdx.x*256 + tid;
    atomicAdd(&lh[char_lengths[w]-1], 1);
    __syncthreads();
    if (tid < 16) hist64[blockIdx.x*16 + tid] = lh[tid];
  }
  int i = blockIdx.x*blockDim.x + tid;
  if (i >= 128*2*100) return;
  int col = i % 100; int d = (i/100) & 1; int c = i/200;
  const float* Wih = d ? cWih_b : cWih_f;
  const float* bb  = d ? cb_b  : cb_f;
  float acc = bb[col];
  #pragma unroll
  for (int k=0;k<25;k++) acc += char_emb[c*25+k]*Wih[k*100+col];
  gxc[i] = acc;
}

// ---------------- k_scan: sum 64 partial histograms, exclusive-scan -> cursor[16].
__global__ void k_scan(const int* __restrict__ hist64, int* __restrict__ cursor){
  __shared__ int tot[16];
  int j = threadIdx.x;
  if (j < 16){
    int acc = 0;
    for (int b=0;b<64;b++) acc += hist64[b*16+j];
    tot[j] = acc;
  }
  __syncthreads();
  if (j == 0){
    int run = 0;
    for (int i=0;i<16;i++){ cursor[i] = run; run += tot[i]; }
  }
}

// ---------------- k_scatter: rank-scatter words into length buckets.
__global__ __launch_bounds__(256) void k_scatter(const int* __restrict__ char_lengths,
                                                 int* __restrict__ cursor,
                                                 int* __restrict__ widx){
  __shared__ int lh[16], lbase[16];
  int tid = threadIdx.x;
  if (tid < 16) lh[tid] = 0;
  __syncthreads();
  int w = blockIdx.x*256 + tid;
  int len = char_lengths[w]-1;
  int lrank = atomicAdd(&lh[len], 1);
  __syncthreads();
  if (tid < 16) lbase[tid] = atomicAdd(&cursor[tid], lh[tid]);
  __syncthreads();
  widx[lbase[len] + lrank] = w;
}

// ---------------- Kernel 1: char BiLSTM over length-sorted words (R16 version).
__global__ __launch_bounds__(512) void k_char(const int* __restrict__ char_tensor,
   const int* __restrict__ char_lengths, const int* __restrict__ widx,
   const float* __restrict__ cWhh_f, const float* __restrict__ cWhh_b,
   const float* __restrict__ gxc, float* __restrict__ cf){
  __shared__ float h_lds[WPB][28];
  __shared__ float act[WPB][100];
  __shared__ int   chars[WPB][TC];
  __shared__ int   lens[WPB];
  __shared__ int   wids[WPB];
  int tid = threadIdx.x;
  int d  = blockIdx.x & 1;
  int wb = blockIdx.x >> 1;
  int w0 = wb*WPB;
  if (tid < WPB){
    int slot = w0 + tid; if (slot > NWORDS-1) slot = NWORDS-1;
    wids[tid] = widx[slot];
  }
  __syncthreads();
  if (tid < WPB*TC){
    int ww = wids[tid/TC];
    chars[tid/TC][tid%TC] = char_tensor[ww*TC + (tid%TC)];
  }
  if (tid < WPB) lens[tid] = char_lengths[wids[tid]];
  int wsub = tid/100;
  int j    = tid - wsub*100;
  bool gate_thr = tid < WPB*100;
  const float* Wh = d ? cWhh_b : cWhh_f;
  float wcol[25];
  if (gate_thr){
    #pragma unroll
    for (int k=0;k<25;k++) wcol[k] = Wh[k*100 + j];
  }
  if (gate_thr && j < 28) h_lds[wsub][j] = 0.f;
  float c_reg = 0.f, h_last = 0.f;
  __syncthreads();
  int lmax = lens[0];
  #pragma unroll
  for (int q=1;q<WPB;q++) lmax = max(lmax, lens[q]);
  int len = gate_thr ? lens[wsub] : 1;
  bool isg = (j >= 50) && (j < 75);
  float gnext = 0.f;
  if (gate_thr){
    int ci = d ? (len-1) : 0;
    if (ci < 0 || ci >= TC) ci = 0;
    gnext = gxc[(size_t)(chars[wsub][ci]*2+d)*100 + j];
  }
  for (int t=0;t<lmax;t++){
    float gcur = gnext;
    if (gate_thr && t+1 < TC){
      int ci = d ? (len-2-t) : (t+1);
      if (ci < 0 || ci >= TC) ci = 0;
      gnext = gxc[(size_t)(chars[wsub][ci]*2+d)*100 + j];
    }
    if (gate_thr){
      float a0 = gcur, a1 = 0.f, a2 = 0.f, a3 = 0.f;
      const float4* h4 = (const float4*)h_lds[wsub];
      #pragma unroll
      for (int kq=0;kq<6;kq++){
        float4 hq = h4[kq];
        a0 += hq.x*wcol[4*kq];
        a1 += hq.y*wcol[4*kq+1];
        a2 += hq.z*wcol[4*kq+2];
        a3 += hq.w*wcol[4*kq+3];
      }
      a0 += h_lds[wsub][24]*wcol[24];
      float a = (a0+a1)+(a2+a3);
      act[wsub][j] = isg ? tanhf_(a) : sigf(a);
    }
    __syncthreads();
    if (gate_thr && j < 25 && t < len){
      float si = act[wsub][j], sf = act[wsub][25+j], sg = act[wsub][50+j], so = act[wsub][75+j];
      c_reg = sf*c_reg + si*sg;
      float hv = so*tanhf_(c_reg);
      h_lds[wsub][j] = hv;
      h_last = hv;
    }
    __syncthreads();
  }
  if (gate_thr && j < 25){
    int w = wids[wsub];
    cf[(size_t)w*56 + d*28 + j] = h_last;
  }
}

// ---------------- Kernel 3: gx[d][p][400] = wb_d + [word_emb[tok[p]] ++ cf[recover[p]]] @ wWih_d
__global__ __launch_bounds__(256) void k_wih(const int* __restrict__ tok,
    const int* __restrict__ recover,
    const float* __restrict__ word_emb, const float* __restrict__ cf,
    const float* __restrict__ Wf, const float* __restrict__ bf,
    const float* __restrict__ Wb, const float* __restrict__ bbias,
    float* __restrict__ gx){
  __shared__ float As[150][72];
  __shared__ int toks[64], recs[64];
  int tid = threadIdx.x;
  int m0 = (blockIdx.x>>2)*64;
  int nt = blockIdx.x & 3;
  int n0 = nt*256;
  if (tid < 64) toks[tid] = tok[m0 + tid];
  else if (tid < 128) recs[tid-64] = recover[m0 + tid - 64];
  __syncthreads();
  for (int i=tid; i<64*150; i+=256){
    int r = i/150; int k = i - r*150;
    float v;
    if (k < WEd) v = word_emb[(long)toks[r]*WEd + k];
    else {
      int ci = k - WEd;
      int dd = ci/25; int uu = ci - dd*25;
      v = cf[(size_t)recs[r]*56 + dd*28 + uu];
    }
    As[k][r] = v;
  }
  __syncthreads();
  int tn = tid & 31; int tm = tid >> 5;
  int j0 = n0 + tn*8;
  bool colok = j0 < 800;
  int d = (j0 >= 400) ? 1 : 0;
  const float* W = d ? Wb : Wf;
  int jc = j0 - d*400;
  float acc[8][8];
  #pragma unroll
  for (int mi=0;mi<8;mi++)
    #pragma unroll
    for (int ni=0;ni<8;ni++) acc[mi][ni]=0.f;
  if (colok){
    for (int k=0;k<150;k++){
      float4 b0 = *(const float4*)&W[k*400 + jc];
      float4 b1 = *(const float4*)&W[k*400 + jc + 4];
      float4 a0 = *(const float4*)&As[k][tm*8];
      float4 a1 = *(const float4*)&As[k][tm*8+4];
      float av[8] = {a0.x,a0.y,a0.z,a0.w,a1.x,a1.y,a1.z,a1.w};
      float bv[8] = {b0.x,b0.y,b0.z,b0.w,b1.x,b1.y,b1.z,b1.w};
      #pragma unroll
      for (int mi=0;mi<8;mi++)
        #pragma unroll
        for (int ni=0;ni<8;ni++) acc[mi][ni] += av[mi]*bv[ni];
    }
    const float* bptr = d ? bbias : bf;
    float bias[8];
    #pragma unroll
    for (int ni=0;ni<8;ni++) bias[ni] = bptr[jc+ni];
    #pragma unroll
    for (int mi=0;mi<8;mi++){
      int p = m0 + tm*8 + mi;
      float* orow = gx + ((long)d*NWORDS + p)*400 + jc;
      #pragma unroll
      for (int ni=0;ni<8;ni++) orow[ni] = acc[mi][ni] + bias[ni];
    }
  }
}

// ---------------- Kernel 4: word LSTM recurrence (R16 exact — best measured 226us).
__global__ __launch_bounds__(448, 2) void k_wlstm(const float* __restrict__ gx,
     const float* __restrict__ Whf, const float* __restrict__ Whb,
     float* __restrict__ hseq){
  __shared__ float wstage[10000];   // 25 rows x 400 cols, 40KB chunk
  __shared__ float h_lds[100];
  __shared__ float act[400];
  int tid = threadIdx.x;
  int s = blockIdx.x & 63; int d = blockIdx.x >> 6;
  const float* Wh = d ? Whb : Whf;
  int j = tid;
  bool colthr = j < 400;
  float wreg[100];
  #pragma unroll
  for (int ch=0; ch<4; ch++){
    for (int i=tid; i<2500; i+=448)
      ((float4*)wstage)[i] = ((const float4*)(Wh + ch*10000))[i];
    __syncthreads();
    if (colthr){
      #pragma unroll
      for (int kk=0;kk<25;kk++) wreg[ch*25+kk] = wstage[kk*400 + j];
    }
    __syncthreads();
  }
  if (tid < 100) h_lds[tid] = 0.f;
  float c_reg = 0.f;
  const float* gxd = gx + ((long)d*NWORDS + (long)s*256)*400;
  bool isg = (j >= 200) && (j < 300);
  __syncthreads();
  float gnext = 0.f;
  if (colthr) gnext = gxd[(d?255:0)*400 + j];
  for (int t=0;t<256;t++){
    float gcur = gnext;
    if (colthr && t+1 < 256){
      int tn = d ? (255-(t+1)) : (t+1);
      gnext = gxd[tn*400 + j];
    }
    if (colthr){
      float a0 = gcur, a1 = 0.f, a2 = 0.f, a3 = 0.f;
      const float4* h4 = (const float4*)h_lds;
      #pragma unroll
      for (int kq=0;kq<25;kq++){
        float4 hq = h4[kq];
        a0 += hq.x*wreg[4*kq];
        a1 += hq.y*wreg[4*kq+1];
        a2 += hq.z*wreg[4*kq+2];
        a3 += hq.w*wreg[4*kq+3];
      }
      float a = (a0+a1)+(a2+a3);
      act[j] = isg ? tanhf_(a) : sigf(a);
    }
    __syncthreads();   // act visible; all h_lds reads of this step done
    if (tid < 100){
      float si = act[tid], sf = act[100+tid], sg = act[200+tid], so = act[300+tid];
      c_reg = sf*c_reg + si*sg;
      float hv = so*tanhf_(c_reg);
      h_lds[tid] = hv;
      int ttc = d ? (255-t) : t;
      hseq[((long)d*NWORDS + s*256 + ttc)*100 + tid] = hv;
    }
    __syncthreads();   // new h visible
  }
}

// ---------------- Kernel 5: emissions em[p][25] = b_tag + concat(h_f,h_b)[p] @ W_tag
__global__ __launch_bounds__(256) void k_em(const float* __restrict__ hseq,
    const float* __restrict__ Wtag, const float* __restrict__ btag,
    float* __restrict__ em){
  __shared__ float hrow[8][200];
  __shared__ float Ws[5000];
  int tid = threadIdx.x;
  for (int i=tid;i<5000;i+=256) Ws[i] = Wtag[i];
  int p0 = blockIdx.x*8;
  for (int i=tid;i<8*200;i+=256){
    int r = i/200; int k = i - r*200;
    int p = p0+r;
    hrow[r][k] = (k<100) ? hseq[(long)p*100+k] : hseq[((long)NWORDS + p)*100 + (k-100)];
  }
  __syncthreads();
  int r = tid>>5; int c = tid&31;
  if (c<25){
    float acc = btag[c];
    for (int k=0;k<200;k++) acc += hrow[r][k]*Ws[k*25+c];
    em[(long)(p0+r)*25 + c] = acc;
  }
}

// ---------------- Kernel 6: CRF per sequence (1 exp/step via etr precompute).
__global__ __launch_bounds__(64) void k_crf(const float* __restrict__ em,
    const int* __restrict__ tag, const float* __restrict__ trans,
    const float* __restrict__ start, const float* __restrict__ endv,
    float* __restrict__ part){
  int s = blockIdx.x;
  int lane = threadIdx.x;
  const float* emb = em + (long)s*256*25;
  float etr[25];
  #pragma unroll
  for (int k=0;k<25;k++) etr[k] = (lane<25) ? __expf(trans[k*25+lane]) : 0.f;
  float alpha = (lane<25) ? (start[lane] + emb[lane]) : 0.f;
  float enext = (lane<25) ? emb[25+lane] : 0.f;
  for (int t=1;t<256;t++){
    float ecur = enext;
    if (t<255 && lane<25) enext = emb[(t+1)*25 + lane];
    float base = RL(alpha, 0);
    float e = __expf(alpha - base);
    float s0=0.f,s1=0.f,s2=0.f,s3=0.f,s4=0.f;
    #pragma unroll
    for (int k=0;k<5;k++) s0 += RL(e,k)    * etr[k];
    #pragma unroll
    for (int k=0;k<5;k++) s1 += RL(e,5+k)  * etr[5+k];
    #pragma unroll
    for (int k=0;k<5;k++) s2 += RL(e,10+k) * etr[10+k];
    #pragma unroll
    for (int k=0;k<5;k++) s3 += RL(e,15+k) * etr[15+k];
    #pragma unroll
    for (int k=0;k<5;k++) s4 += RL(e,20+k) * etr[20+k];
    float ssum = ((s0+s1)+(s2+s3))+s4;
    alpha = __logf(ssum) + base + ecur;
  }
  float val = (lane<25) ? (alpha + endv[lane]) : -1e30f;
  float m2 = -1e30f;
  #pragma unroll
  for (int k=0;k<25;k++) m2 = fmaxf(m2, RL(val,k));
  float s2s = 0.f;
  #pragma unroll
  for (int k=0;k<25;k++) s2s += __expf(RL(val,k) - m2);
  float logZ = __logf(s2s) + m2;
  const int* tg = tag + s*256;
  float gp = 0.f;
  for (int t=lane; t<256; t+=64){
    int a = tg[t];
    gp += emb[t*25 + a];
    if (t<255) gp += trans[a*25 + tg[t+1]];
  }
  #pragma unroll
  for (int off=32; off; off>>=1) gp += __shfl_xor(gp, off, 64);
  if (lane==0){
    float gold = gp + start[tg[0]] + endv[tg[255]];
    part[s] = logZ - gold;
  }
}

// ---------------- Kernel 7: final reduce
__global__ __launch_bounds__(64) void k_red(const float* __restrict__ part, float* __restrict__ out){
  float v = part[threadIdx.x];
  #pragma unroll
  for (int off=32; off; off>>=1) v += __shfl_xor(v, off, 64);
  if (threadIdx.x==0) out[0] = v;
}

extern "C" void kernel_launch(void* const* d_in, const int* in_sizes, int n_in,
                              void* d_out, int out_size, void* d_ws, size_t ws_size,
                              hipStream_t stream){
  const int* tok          = (const int*)d_in[0];
  const int* tagp         = (const int*)d_in[1];
  const int* char_tensor  = (const int*)d_in[3];
  const int* char_lengths = (const int*)d_in[4];
  const int* recover      = (const int*)d_in[5];
  const float* word_emb = (const float*)d_in[6];
  const float* char_emb = (const float*)d_in[7];
  const float* cWih_f=(const float*)d_in[8];  const float* cWhh_f=(const float*)d_in[9];  const float* cb_f=(const float*)d_in[10];
  const float* cWih_b=(const float*)d_in[11]; const float* cWhh_b=(const float*)d_in[12]; const float* cb_b=(const float*)d_in[13];
  const float* wWih_f=(const float*)d_in[14]; const float* wWhh_f=(const float*)d_in[15]; const float* wb_f=(const float*)d_in[16];
  const float* wWih_b=(const float*)d_in[17]; const float* wWhh_b=(const float*)d_in[18]; const float* wb_b=(const float*)d_in[19];
  const float* W_tag=(const float*)d_in[20];  const float* b_tag=(const float*)d_in[21];
  const float* trans=(const float*)d_in[22];  const float* startv=(const float*)d_in[23]; const float* endv=(const float*)d_in[24];

  float* ws  = (float*)d_ws;
  float* gxc = ws;                 // [0, 25600)
  float* cf  = ws + 25600;         // [25600, 943104)
  float* gx  = ws + 943104;        // [943104, 14050304)
  float* hseq= ws + 14050304;      // [14050304, 17327104)
  float* em  = ws;                 // overlays gxc+cf (dead after k_wih), 409600
  float* part= ws + 17327104;      // 64
  int*   hist64 = (int*)(ws + 17327168);  // 64*16 = 1024 ints
  int*   cursor = hist64 + 1024;          // 16 ints
  int*   widx   = hist64 + 1088;          // 16384 ints (high water ~69.4 MB)
  float* out = (float*)d_out;

  k_gxc    <<<100, 256, 0, stream>>>(char_emb, cWih_f, cb_f, cWih_b, cb_b, char_lengths, gxc, hist64);
  k_scan   <<<1,   64,  0, stream>>>(hist64, cursor);
  k_scatter<<<64,  256, 0, stream>>>(char_lengths, cursor, widx);
  k_char   <<<6554,512, 0, stream>>>(char_tensor, char_lengths, widx, cWhh_f, cWhh_b, gxc, cf);
  k_wih    <<<1024,256, 0, stream>>>(tok, recover, word_emb, cf, wWih_f, wb_f, wWih_b, wb_b, gx);
  k_wlstm  <<<128, 448, 0, stream>>>(gx, wWhh_f, wWhh_b, hseq);
  k_em     <<<2048,256, 0, stream>>>(hseq, W_tag, b_tag, em);
  k_crf    <<<64,  64,  0, stream>>>(em, tagp, trans, startv, endv, part);
  k_red    <<<1,   64,  0, stream>>>(part, out);
}